// Round 5
// baseline (269.301 us; speedup 1.0000x reference)
//
#include <hip/hip_runtime.h>
#include <math.h>

// Tropical (max-plus) matmul: out[b,o] = max_k ( x[b,k] + W[o,k] )
// x: (2048,512) f32, W: (512,512) f32, out: (2048,512) f32.
//
// R7 post-mortem: 512t blocks worked (main 57-68 -> 41.4us profiled,
// VALUBusy 25->39%) but e2e rose: timed = poison(40, fixed) + main(41) +
// SK16-reduce(15, cold 68MB) + misc. Main still dependency-bound: LDS pipe
// ~25% busy, VALU ~39% -> neither saturated; waves stall on lgkmcnt after
// each kp's 8 reads (barrier-aligned phases). 8 waves/SIMD impossible
// (acc=64 VGPR), so attack with ILP.
// R8: (a) software-pipelined kp loop: A double-buffered (Aa/Ab), B
// reloaded in halves between its uses -> every ds_read covered by 64-128
// VALU instrs; ~120 VGPR, still 4 waves/SIMD. (b) reduce blocks remapped
// rbx = T + 32*s so each reduce block runs on the XCD (T%8) whose main
// blocks wrote its partials -> partial L2 hits on the 64MB re-read.

typedef float f2v __attribute__((ext_vector_type(2)));
typedef float f4v __attribute__((ext_vector_type(4)));

#define B_ROWS 2048
#define K_DIM  512
#define O_DIM  512
#define BM 256
#define BN 128
#define BK 32
#define SPLITK 16
#define KRANGE (K_DIM / SPLITK)   // 32 = BK -> single k-tile per block

__device__ __forceinline__ void atomic_max_f32(float* p, float v) {
    unsigned int* up = (unsigned int*)p;
    unsigned int cur = *(volatile unsigned int*)up;
    while (__uint_as_float(cur) < v) {
        unsigned int assumed = cur;
        cur = atomicCAS(up, assumed, __float_as_uint(v));
        if (cur == assumed) break;
    }
}

template <bool USE_WS>
__global__ __launch_bounds__(512, 2) void tropical_main(
    const float* __restrict__ x, const float* __restrict__ W,
    float* __restrict__ dst)  // USE_WS: ws partials base; else d_out
{
    // k-pair-major LDS: [kp][row] = { v[2kp][row], v[2kp+1][row] }.
    __shared__ __align__(16) f2v xs2[BK / 2][BM];   // 32 KB
    __shared__ __align__(16) f2v ws2[BK / 2][BN];   // 16 KB

    const int t  = threadIdx.x;
    const int bx = blockIdx.x;
    const int bn = (bx & 3) * BN;          // 4 N-tiles
    const int bm = ((bx >> 2) & 7) * BM;   // 8 M-tiles
    const int ks = bx >> 5;                // 16 K-splits; bx&31 = tile id T
    const int k0 = ks * KRANGE;

    // ---- staging (single k-tile) ----
    const int rowA = t & 255;
    const int khA  = t >> 8;               // 0/1 -> k-offset 16*khA
    const int rowB = t & 127;
    const int khB  = (t >> 7) & 1;
    const bool doB = t < 256;

    const float* xb = x + (size_t)(bm + rowA) * K_DIM + k0 + 16 * khA;
    const float* wb = W + (size_t)(bn + rowB) * K_DIM + k0 + 16 * khB;

    float4 pa[4], pb[4];
#pragma unroll
    for (int q = 0; q < 4; ++q) pa[q] = *(const float4*)(xb + 4 * q);
    if (doB) {
#pragma unroll
        for (int q = 0; q < 4; ++q) pb[q] = *(const float4*)(wb + 4 * q);
    }

#pragma unroll
    for (int q = 0; q < 4; ++q) {
        const int kp = 8 * khA + 2 * q;
        xs2[kp][rowA]     = (f2v){pa[q].x, pa[q].y};
        xs2[kp + 1][rowA] = (f2v){pa[q].z, pa[q].w};
    }
    if (doB) {
#pragma unroll
        for (int q = 0; q < 4; ++q) {
            const int kp = 8 * khB + 2 * q;
            ws2[kp][rowB]     = (f2v){pb[q].x, pb[q].y};
            ws2[kp + 1][rowB] = (f2v){pb[q].z, pb[q].w};
        }
    }
    __syncthreads();

    // ---- compute: 16x32 thread grid, 8x8 register tile, pipelined ----
    const int tx = t & 15;
    const int ty = t >> 4;                 // 0..31
    const int c0 = tx * 4, c1 = 64 + tx * 4;
    const int r0 = ty * 4, r1 = 128 + ty * 4;

    float acc[2][4][2][4];  // [ri][i][ci][j]
#pragma unroll
    for (int ri = 0; ri < 2; ++ri)
#pragma unroll
        for (int i = 0; i < 4; ++i)
#pragma unroll
            for (int ci = 0; ci < 2; ++ci)
#pragma unroll
                for (int j = 0; j < 4; ++j) acc[ri][i][ci][j] = -INFINITY;

    f4v Aa[2][2], Ab[2][2], Bf[2][2];

#define LOAD_A(dstA, kp) do {                                         \
        dstA[0][0] = *(const f4v*)&xs2[kp][r0];                       \
        dstA[0][1] = *(const f4v*)&xs2[kp][r0 + 2];                   \
        dstA[1][0] = *(const f4v*)&xs2[kp][r1];                       \
        dstA[1][1] = *(const f4v*)&xs2[kp][r1 + 2];                   \
    } while (0)
#define LOAD_B0(kp) do {                                              \
        Bf[0][0] = *(const f4v*)&ws2[kp][c0];                         \
        Bf[0][1] = *(const f4v*)&ws2[kp][c0 + 2];                     \
    } while (0)
#define LOAD_B1(kp) do {                                              \
        Bf[1][0] = *(const f4v*)&ws2[kp][c1];                         \
        Bf[1][1] = *(const f4v*)&ws2[kp][c1 + 2];                     \
    } while (0)
// 64 VALU ops per half: pk_add + max3, operands are subreg halves.
#define COMP_CI(A, ci) do {                                           \
        _Pragma("unroll")                                             \
        for (int ri = 0; ri < 2; ++ri) {                              \
            _Pragma("unroll")                                         \
            for (int i = 0; i < 4; ++i) {                             \
                const f2v a =                                         \
                    (i & 1) ? (f2v){A[ri][i >> 1].z, A[ri][i >> 1].w} \
                            : (f2v){A[ri][i >> 1].x, A[ri][i >> 1].y};\
                _Pragma("unroll")                                     \
                for (int j = 0; j < 4; ++j) {                         \
                    const f2v b = (j & 1)                             \
                        ? (f2v){Bf[ci][j >> 1].z, Bf[ci][j >> 1].w}   \
                        : (f2v){Bf[ci][j >> 1].x, Bf[ci][j >> 1].y};  \
                    f2v s = a + b;               /* v_pk_add_f32 */   \
                    acc[ri][i][ci][j] =                               \
                        fmaxf(acc[ri][i][ci][j],                      \
                              fmaxf(s.x, s.y));  /* v_max3_f32  */    \
                }                                                     \
            }                                                         \
        }                                                             \
    } while (0)
// Pipelined step: prefetch kp+1 while computing kp; B halves reloaded
// between their two uses (WAR-safe by program order).
#define STEP(kp, CUR, NXT) do {                                       \
        LOAD_A(NXT, (kp) + 1);                                        \
        COMP_CI(CUR, 0);                                              \
        LOAD_B0((kp) + 1);                                            \
        COMP_CI(CUR, 1);                                              \
        LOAD_B1((kp) + 1);                                            \
    } while (0)

    LOAD_A(Aa, 0); LOAD_B0(0); LOAD_B1(0);
    STEP(0,  Aa, Ab); STEP(1,  Ab, Aa);
    STEP(2,  Aa, Ab); STEP(3,  Ab, Aa);
    STEP(4,  Aa, Ab); STEP(5,  Ab, Aa);
    STEP(6,  Aa, Ab); STEP(7,  Ab, Aa);
    STEP(8,  Aa, Ab); STEP(9,  Ab, Aa);
    STEP(10, Aa, Ab); STEP(11, Ab, Aa);
    STEP(12, Aa, Ab); STEP(13, Ab, Aa);
    STEP(14, Aa, Ab);
    COMP_CI(Ab, 0);   // kp = 15, no prefetch
    COMP_CI(Ab, 1);

#undef LOAD_A
#undef LOAD_B0
#undef LOAD_B1
#undef COMP_CI
#undef STEP

    // ---- epilogue ----
    if (USE_WS) {
        float* outp = dst + (size_t)ks * (B_ROWS * O_DIM);
#pragma unroll
        for (int ri = 0; ri < 2; ++ri) {
            const int rb = bm + (ri ? r1 : r0);
#pragma unroll
            for (int i = 0; i < 4; ++i) {
                float4 v0, v1;
                v0.x = acc[ri][i][0][0]; v0.y = acc[ri][i][0][1];
                v0.z = acc[ri][i][0][2]; v0.w = acc[ri][i][0][3];
                v1.x = acc[ri][i][1][0]; v1.y = acc[ri][i][1][1];
                v1.z = acc[ri][i][1][2]; v1.w = acc[ri][i][1][3];
                *(float4*)(outp + (size_t)(rb + i) * O_DIM + bn + c0) = v0;
                *(float4*)(outp + (size_t)(rb + i) * O_DIM + bn + c1) = v1;
            }
        }
    } else {
#pragma unroll
        for (int ri = 0; ri < 2; ++ri) {
            const int rb = bm + (ri ? r1 : r0);
#pragma unroll
            for (int i = 0; i < 4; ++i)
#pragma unroll
                for (int ci = 0; ci < 2; ++ci)
#pragma unroll
                    for (int j = 0; j < 4; ++j) {
                        const int gc = bn + (ci ? c1 : c0) + j;
                        atomic_max_f32(dst + (size_t)(rb + i) * O_DIM + gc,
                                       acc[ri][i][ci][j]);
                    }
        }
    }
}

// XCD-aligned reduce: block rbx = T + 32*s handles tile T = main's (bx&31)
// (rows (T>>2)*256 + s*32 .. +31, cols (T&3)*128 .. +127). rbx%8 == T%8 ==
// the XCD whose main blocks wrote tile T's partials -> partial L2 hits.
__global__ __launch_bounds__(256) void tropical_reduce(
    const float4* __restrict__ ws, float4* __restrict__ out)
{
    const int rbx = blockIdx.x;        // 0..255
    const int T = rbx & 31;
    const int s = rbx >> 5;            // 0..7
    const int n = T & 3, m = T >> 2;
    const int t = threadIdx.x;
    const int Q = B_ROWS * O_DIM / 4;  // 262144 f4 per split
#pragma unroll
    for (int u = 0; u < 4; ++u) {
        const int e   = t + 256 * u;             // 0..1023
        const int row = m * 256 + s * 32 + (e >> 5);
        const int c4  = n * 32 + (e & 31);       // col/4
        const int idx = row * (O_DIM / 4) + c4;
        float4 r = ws[idx];
#pragma unroll
        for (int p = 1; p < SPLITK; ++p) {
            float4 v = ws[idx + p * Q];
            r.x = fmaxf(r.x, v.x);
            r.y = fmaxf(r.y, v.y);
            r.z = fmaxf(r.z, v.z);
            r.w = fmaxf(r.w, v.w);
        }
        out[idx] = r;
    }
}

__global__ __launch_bounds__(256) void tropical_fill(float4* __restrict__ out)
{
    const int i = blockIdx.x * 256 + threadIdx.x;
    out[i] = make_float4(-INFINITY, -INFINITY, -INFINITY, -INFINITY);
}

extern "C" void kernel_launch(void* const* d_in, const int* in_sizes, int n_in,
                              void* d_out, int out_size, void* d_ws, size_t ws_size,
                              hipStream_t stream) {
    const float* x = (const float*)d_in[0];   // (2048, 512)
    const float* W = (const float*)d_in[1];   // (512, 512)
    float* out = (float*)d_out;               // (2048, 512)

    const size_t partial_bytes =
        (size_t)SPLITK * B_ROWS * O_DIM * sizeof(float);     // 64 MB
    const int nblocks = 8 * 4 * SPLITK;                      // 512
    const int nfill = (B_ROWS * O_DIM / 4) / 256;            // 1024

    if (ws_size >= partial_bytes) {
        tropical_main<true><<<nblocks, 512, 0, stream>>>(x, W, (float*)d_ws);
        tropical_reduce<<<256, 256, 0, stream>>>(
            (const float4*)d_ws, (float4*)out);
    } else {
        tropical_fill<<<nfill, 256, 0, stream>>>((float4*)out);
        tropical_main<false><<<nblocks, 512, 0, stream>>>(x, W, out);
    }
}

// Round 6
// 65.282 us; speedup vs baseline: 4.1252x; 4.1252x over previous
//
#include <hip/hip_runtime.h>
#include <math.h>

// Tropical (max-plus) matmul: out[b,o] = max_k ( x[b,k] + W[o,k] )
// x: (2048,512) f32, W: (512,512) f32, out: (2048,512) f32.
//
// R8 post-mortem: manual pipeline spilled (VGPR=128 clamp, 514MB scratch
// writes, 203us). Full-compute approach is cornered: VALU-issue ~16us,
// LDS ~10us, stalls dominate at <=4 waves/SIMD -> main >= ~40us + reduce.
// R9: change the arithmetic. EXACT candidate pruning: for ANY k with
// x[b,k] < m_b - (Wmax - Wmin):  x+W[o,k] < m_b + Wmin <= m_b + W[o,k*]
// for k* = argmax_k x[b,k], for every o. So out[b,o] = max over the
// candidate set {k : x[b,k] >= m_b - dW} -- ~2-5 of 512 for this data
// (W = 0.05*N(0,1) -> dW ~ 0.45; x spread ~8). Bit-exact (same f32 adds,
// max over a superset of the argmax), correct for ANY input (loop handles
// any candidate count, worst case = full scan).
// K1: transpose W -> Wt (ws) for coalesced column reads + block min/max.
// K2: wave-per-row: row max, dW, ballot candidates, broadcast each
// (k, xv), acc[o] = max(acc[o], xv + Wt[k][o]). ~9MB HBM total.

#define B_ROWS 2048
#define K_DIM  512
#define O_DIM  512

// ws layout (floats): [0..127] 64 (min,max) pairs; Wt at float offset 256.
#define WS_WT_OFF 256
#define WS_NEED_BYTES ((size_t)(WS_WT_OFF + K_DIM * O_DIM) * sizeof(float))

__global__ __launch_bounds__(256) void prep_transpose_minmax(
    const float* __restrict__ W, float* __restrict__ ws)
{
    __shared__ float sm[64][65];      // 64x64 tile, padded
    __shared__ float wmin[4], wmax[4];

    const int t  = threadIdx.x;
    const int bx = blockIdx.x;        // 64 blocks: 8x8 tiles of 64x64
    const int tr = (bx >> 3) * 64;    // o-dim (W row) tile base
    const int tc = (bx & 7) * 64;     // k-dim (W col) tile base

    const int lr0 = t >> 4;           // 0..15
    const int lc  = (t & 15) * 4;     // 0..60

    float lmin = INFINITY, lmax = -INFINITY;
#pragma unroll
    for (int q = 0; q < 4; ++q) {
        const int r = lr0 + q * 16;
        float4 v = *(const float4*)(W + (size_t)(tr + r) * K_DIM + tc + lc);
        sm[r][lc + 0] = v.x; sm[r][lc + 1] = v.y;
        sm[r][lc + 2] = v.z; sm[r][lc + 3] = v.w;
        lmin = fminf(lmin, fminf(fminf(v.x, v.y), fminf(v.z, v.w)));
        lmax = fmaxf(lmax, fmaxf(fmaxf(v.x, v.y), fmaxf(v.z, v.w)));
    }
    __syncthreads();

    // transposed write: Wt[k][o]
    float* Wt = ws + WS_WT_OFF;
#pragma unroll
    for (int q = 0; q < 4; ++q) {
        const int kr = lr0 + q * 16;
        float4 v;
        v.x = sm[lc + 0][kr]; v.y = sm[lc + 1][kr];
        v.z = sm[lc + 2][kr]; v.w = sm[lc + 3][kr];
        *(float4*)(Wt + (size_t)(tc + kr) * O_DIM + tr + lc) = v;
    }

    // block min/max -> ws[2*bx], ws[2*bx+1]
#pragma unroll
    for (int off = 32; off; off >>= 1) {
        lmin = fminf(lmin, __shfl_xor(lmin, off));
        lmax = fmaxf(lmax, __shfl_xor(lmax, off));
    }
    if ((t & 63) == 0) { wmin[t >> 6] = lmin; wmax[t >> 6] = lmax; }
    __syncthreads();
    if (t == 0) {
        ws[2 * bx]     = fminf(fminf(wmin[0], wmin[1]), fminf(wmin[2], wmin[3]));
        ws[2 * bx + 1] = fmaxf(fmaxf(wmax[0], wmax[1]), fmaxf(wmax[2], wmax[3]));
    }
}

__global__ __launch_bounds__(256) void tropical_sparse(
    const float* __restrict__ x, const float* __restrict__ ws,
    float* __restrict__ out)
{
    const int t    = threadIdx.x;
    const int w    = t >> 6;                  // wave 0..3
    const int lane = t & 63;
    const int b    = blockIdx.x * 4 + w;      // row, 512 blocks x 4 = 2048
    const float* Wt = ws + WS_WT_OFF;

    // x row: 8 consecutive floats per lane (k = lane*8 .. +7)
    const float* xr = x + (size_t)b * K_DIM + lane * 8;
    float4 xa = *(const float4*)(xr);
    float4 xb = *(const float4*)(xr + 4);
    float xs[8] = {xa.x, xa.y, xa.z, xa.w, xb.x, xb.y, xb.z, xb.w};

    // global W min/max from the 64 per-block pairs (lane l reads pair l)
    float bmin = ws[2 * lane], bmax = ws[2 * lane + 1];
#pragma unroll
    for (int off = 32; off; off >>= 1) {
        bmin = fminf(bmin, __shfl_xor(bmin, off));
        bmax = fmaxf(bmax, __shfl_xor(bmax, off));
    }
    const float dW = bmax - bmin;

    // row max
    float m = xs[0];
#pragma unroll
    for (int i = 1; i < 8; ++i) m = fmaxf(m, xs[i]);
#pragma unroll
    for (int off = 32; off; off >>= 1) m = fmaxf(m, __shfl_xor(m, off));
    const float thr = m - dW;

    float acc[8];
#pragma unroll
    for (int i = 0; i < 8; ++i) acc[i] = -INFINITY;

    const int o0 = lane * 8;
    // candidates: any k with x[b,k] >= thr (>=1 exists: the argmax itself)
#pragma unroll
    for (int s = 0; s < 8; ++s) {
        unsigned long long mask = __ballot(xs[s] >= thr);
        while (mask) {
            const int src = __ffsll((unsigned long long)mask) - 1;
            mask &= mask - 1;
            const float xv = __shfl(xs[s], src);
            const int k = src * 8 + s;
            const float* wr = Wt + (size_t)k * O_DIM + o0;
            float4 wa = *(const float4*)(wr);
            float4 wb = *(const float4*)(wr + 4);
            acc[0] = fmaxf(acc[0], xv + wa.x);
            acc[1] = fmaxf(acc[1], xv + wa.y);
            acc[2] = fmaxf(acc[2], xv + wa.z);
            acc[3] = fmaxf(acc[3], xv + wa.w);
            acc[4] = fmaxf(acc[4], xv + wb.x);
            acc[5] = fmaxf(acc[5], xv + wb.y);
            acc[6] = fmaxf(acc[6], xv + wb.z);
            acc[7] = fmaxf(acc[7], xv + wb.w);
        }
    }

    float* op = out + (size_t)b * O_DIM + o0;
    float4 r0, r1;
    r0.x = acc[0]; r0.y = acc[1]; r0.z = acc[2]; r0.w = acc[3];
    r1.x = acc[4]; r1.y = acc[5]; r1.z = acc[6]; r1.w = acc[7];
    *(float4*)(op)     = r0;
    *(float4*)(op + 4) = r1;
}

// ws-too-small fallback (never expected to run; ws has been >=64MB):
// plain full scan, correct for any input.
__global__ __launch_bounds__(256) void tropical_naive(
    const float* __restrict__ x, const float* __restrict__ W,
    float* __restrict__ out)
{
    const int b = blockIdx.x;
    const int t = threadIdx.x;
#pragma unroll
    for (int half = 0; half < 2; ++half) {
        const int o = t + half * 256;
        const float* wr = W + (size_t)o * K_DIM;
        const float* xr = x + (size_t)b * K_DIM;
        float acc = -INFINITY;
        for (int k = 0; k < K_DIM; ++k)
            acc = fmaxf(acc, xr[k] + wr[k]);
        out[(size_t)b * O_DIM + o] = acc;
    }
}

extern "C" void kernel_launch(void* const* d_in, const int* in_sizes, int n_in,
                              void* d_out, int out_size, void* d_ws, size_t ws_size,
                              hipStream_t stream) {
    const float* x = (const float*)d_in[0];   // (2048, 512)
    const float* W = (const float*)d_in[1];   // (512, 512)
    float* out = (float*)d_out;               // (2048, 512)

    if (ws_size >= WS_NEED_BYTES) {
        prep_transpose_minmax<<<64, 256, 0, stream>>>(W, (float*)d_ws);
        tropical_sparse<<<B_ROWS / 4, 256, 0, stream>>>(
            x, (const float*)d_ws, out);
    } else {
        tropical_naive<<<B_ROWS, 256, 0, stream>>>(x, W, out);
    }
}